// Round 21
// baseline (222.051 us; speedup 1.0000x reference)
//
#include <hip/hip_runtime.h>

// Neural-ODE, f(y) = tanh(y@W1+b1)@W2 + b2, 20800 independent 64-dim points.
// R21: FUSED single kernel. R20's two-kernel split existed only to avoid the
// R12-R14 register spill; but kernel2 consumed only records produced by the
// SAME block's points -> no cross-block dataflow. Fusion done spill-safe:
//   phase 1: R20 kernel1 VERBATIM shape (rolled RK4 stage loop, SEG_CAP-merged
//            segments), records {y0,f0} f16-packed to LDS (not global);
//            Hermite coefficients computed per segment by lane 0 into LDS.
//   phase 2: AFTER the integration loop (separate phase, fresh registers,
//            simple CFG): per point, Hermite-expand 24 outputs from LDS
//            records, float4 stores. One wave/block -> no barriers anywhere.
// SEG_CAP 0.25 -> 0.30 (absmax sat at the 1-ulp bf16 floor for 0.15/0.20/
// 0.25; predicted <= 2 ulp at 0.30). Worst-case nseg = 12 -> 13 record slots.
// LDS: 16 pts x 834 dwords (13 slots x 64 + 2 pad) = 53.4 KB < 64 KB.
// No d_ws needed at all. Per-feval machinery R8-R10-verified.

#define NB 64
#define NPT 325
#define ND 64
#define NH 128
#define NTOUT 24
#define GP16 21                   // ceil(325/16)
#define NTASK (NB * GP16)         // 1344 single-wave blocks
#define SEG_CAP 0.30f             // max RK4 step span (dt in [0.01,0.1])
#define SLOTS 13                  // worst-case segments+1 (2 intervals/seg)
#define RSTRIDE (SLOTS * 64 + 2)  // 834 dwords: bank-spread pad

using f16x8 = __attribute__((ext_vector_type(8))) _Float16;
using f16x2 = __attribute__((ext_vector_type(2))) _Float16;
using f32x4 = __attribute__((ext_vector_type(4))) float;
using u32x4 = __attribute__((ext_vector_type(4))) unsigned;

__device__ __forceinline__ unsigned pack2(float lo, float hi) {
  auto pk = __builtin_amdgcn_cvt_pkrtz(lo, hi);
  return __builtin_bit_cast(unsigned, pk);
}

__device__ __forceinline__ f16x8 frag4(unsigned a, unsigned b, unsigned c, unsigned d) {
  u32x4 u = {a, b, c, d};
  return __builtin_bit_cast(f16x8, u);
}

__device__ __forceinline__ float h16(unsigned u, int hi) {
  f16x2 h = __builtin_bit_cast(f16x2, u);
  return (float)h[hi];
}

__global__ __launch_bounds__(64, 2) void node_fused_kernel(
    const float* __restrict__ y0g, const float* __restrict__ tsg,
    const float* __restrict__ W1g, const float* __restrict__ b1g,
    const float* __restrict__ W2g, const float* __restrict__ b2g,
    float* __restrict__ outg) {
  __shared__ float ts_s[NTOUT];
  __shared__ float c0s[NTOUT], c1s[NTOUT], c2s[NTOUT], c3s[NTOUT];
  __shared__ int sidx[NTOUT];
  __shared__ unsigned recs[16 * RSTRIDE];  // 53.4 KB f16 records

  const int lane = threadIdx.x & 63;
  const int c = lane & 15;
  const int g = lane >> 4;

  const int task = blockIdx.x;
  const int b = task / GP16;
  const int p0 = (task - b * GP16) * 16;

  if (lane < NTOUT) ts_s[lane] = tsg[lane * NB + b];
  // single wave: in-order LDS write->read, no barrier needed anywhere

  const float SC = 2.885390081777927f;  // 2*log2(e), folded into W1/b1

  // ---- weights as fp16 A-frags with pi-permuted k-order ----
  f16x8 wf1[8][2];
#pragma unroll
  for (int rt = 0; rt < 8; ++rt)
#pragma unroll
    for (int kt = 0; kt < 2; ++kt) {
      f16x8 a;
#pragma unroll
      for (int j = 0; j < 8; ++j) {
        int ek = 4 * g + (j & 3) + ((j >> 2) << 4);
        a[j] = (_Float16)(W1g[(32 * kt + ek) * NH + 16 * rt + c] * SC);
      }
      wf1[rt][kt] = a;
    }
  f16x8 wf2[4][4];
#pragma unroll
  for (int rt = 0; rt < 4; ++rt)
#pragma unroll
    for (int kt = 0; kt < 4; ++kt) {
      f16x8 a;
#pragma unroll
      for (int j = 0; j < 8; ++j) {
        int ek = 4 * g + (j & 3) + ((j >> 2) << 4);
        a[j] = (_Float16)W2g[(32 * kt + ek) * ND + 16 * rt + c];
      }
      wf2[rt][kt] = a;
    }

  f32x4 b1C[8], b2C[4];
#pragma unroll
  for (int rt = 0; rt < 8; ++rt)
#pragma unroll
    for (int q = 0; q < 4; ++q) b1C[rt][q] = b1g[16 * rt + 4 * g + q] * SC;
#pragma unroll
  for (int rt = 0; rt < 4; ++rt)
#pragma unroll
    for (int q = 0; q < 4; ++q) b2C[rt][q] = b2g[16 * rt + 4 * g + q];

  const int ptc = p0 + c;
  const int qpt = b * NPT + min(ptc, NPT - 1);
  // clamped lanes integrate the last point duplicate (benign; skipped in phase 2)

  float y[16], y5[16];
#pragma unroll
  for (int mt = 0; mt < 4; ++mt) {
    float4 v = *(const float4*)&y0g[qpt * ND + 16 * mt + 4 * g];
    y[4 * mt + 0] = v.x; y[4 * mt + 1] = v.y;
    y[4 * mt + 2] = v.z; y[4 * mt + 3] = v.w;
  }

  f16x8 yb0, yb1;
  auto mkyb = [&](const float* v) {
    yb0 = frag4(pack2(v[0], v[1]), pack2(v[2], v[3]),
                pack2(v[4], v[5]), pack2(v[6], v[7]));
    yb1 = frag4(pack2(v[8], v[9]), pack2(v[10], v[11]),
                pack2(v[12], v[13]), pack2(v[14], v[15]));
  };

  const f32x4 zf = {0.0f, 0.0f, 0.0f, 0.0f};
  f32x4 acc2[4];
  auto feval = [&]() {
    f32x4 acc[8];
#pragma unroll
    for (int rt = 0; rt < 8; ++rt) {
      f32x4 tA = __builtin_amdgcn_mfma_f32_16x16x32_f16(wf1[rt][0], yb0, b1C[rt], 0, 0, 0);
      f32x4 tB = __builtin_amdgcn_mfma_f32_16x16x32_f16(wf1[rt][1], yb1, zf, 0, 0, 0);
      acc[rt] = tA + tB;
    }
    float th[32];
#pragma unroll
    for (int i = 0; i < 32; ++i) th[i] = __builtin_exp2f(acc[i >> 2][i & 3]);
#pragma unroll
    for (int i = 0; i < 32; ++i) th[i] = __builtin_amdgcn_rcpf(th[i] + 1.0f);
    f16x8 hb[4];
#pragma unroll
    for (int kt = 0; kt < 4; ++kt) {
      hb[kt] = frag4(
          pack2(fmaf(-2.0f, th[8 * kt + 0], 1.0f), fmaf(-2.0f, th[8 * kt + 1], 1.0f)),
          pack2(fmaf(-2.0f, th[8 * kt + 2], 1.0f), fmaf(-2.0f, th[8 * kt + 3], 1.0f)),
          pack2(fmaf(-2.0f, th[8 * kt + 4], 1.0f), fmaf(-2.0f, th[8 * kt + 5], 1.0f)),
          pack2(fmaf(-2.0f, th[8 * kt + 6], 1.0f), fmaf(-2.0f, th[8 * kt + 7], 1.0f)));
    }
#pragma unroll
    for (int rt = 0; rt < 4; ++rt) {
      f32x4 tA = __builtin_amdgcn_mfma_f32_16x16x32_f16(wf2[rt][0], hb[0], b2C[rt], 0, 0, 0);
      tA = __builtin_amdgcn_mfma_f32_16x16x32_f16(wf2[rt][1], hb[1], tA, 0, 0, 0);
      f32x4 tB = __builtin_amdgcn_mfma_f32_16x16x32_f16(wf2[rt][2], hb[2], zf, 0, 0, 0);
      tB = __builtin_amdgcn_mfma_f32_16x16x32_f16(wf2[rt][3], hb[3], tB, 0, 0, 0);
      acc2[rt] = tA + tB;
    }
  };

#define FV(i) (acc2[(i) >> 2][(i) & 3])

  // record {y0[64] f16, f0[64] f16} for this wave's 16 points, slot s, in LDS
  auto store_rec = [&](int s) {
    unsigned* rp = &recs[c * RSTRIDE + s * 64 + 2 * g];
#pragma unroll
    for (int mt = 0; mt < 4; ++mt) {
      *(uint2*)&rp[8 * mt] = make_uint2(pack2(y[4 * mt], y[4 * mt + 1]),
                                        pack2(y[4 * mt + 2], y[4 * mt + 3]));
      *(uint2*)&rp[32 + 8 * mt] = make_uint2(pack2(FV(4 * mt), FV(4 * mt + 1)),
                                             pack2(FV(4 * mt + 2), FV(4 * mt + 3)));
    }
  };

  // ======================= phase 1: integrate ==============================
  float t0 = ts_s[0];
  mkyb(y);

  int s = 0;
  int k = 1;
#pragma unroll 1
  while (k < NTOUT) {
    int kend = k;
    float tend = ts_s[k];
#pragma unroll 1
    while (kend + 1 < NTOUT) {
      float tn = ts_s[kend + 1];
      if (tn - t0 <= SEG_CAP) { kend = kend + 1; tend = tn; } else break;
    }
    const float H = tend - t0;
    const float H2 = 0.5f * H;
    const float H6 = H * (1.0f / 6.0f);
    const float H3 = 2.0f * H6;

    if (lane == 0) {  // Hermite coefficients for this segment's output times
#pragma unroll 1
      for (int kk = k; kk <= kend; ++kk) {
        float th = (ts_s[kk] - t0) / H;
        float th2 = th * th, th3 = th2 * th;
        c0s[kk] = 2.0f * th3 - 3.0f * th2 + 1.0f;
        c1s[kk] = (th3 - 2.0f * th2 + th) * H;
        c2s[kk] = 3.0f * th2 - 2.0f * th3;
        c3s[kk] = (th3 - th2) * H;
        sidx[kk] = s;
      }
    }

#pragma unroll
    for (int i = 0; i < 16; ++i) y5[i] = y[i];

#pragma unroll 1
    for (int st = 0; st < 4; ++st) {  // rolled stage loop (spill-free shape)
      feval();
      if (st == 0) store_rec(s);  // uniform branch: {y0, k1}
      const float cB = (st == 0 || st == 3) ? H6 : H3;
#pragma unroll
      for (int i = 0; i < 16; ++i) y5[i] = fmaf(cB, FV(i), y5[i]);
      if (st < 3) {
        const float cA = (st == 2) ? H : H2;
        float yt[16];
#pragma unroll
        for (int i = 0; i < 16; ++i) yt[i] = fmaf(cA, FV(i), y[i]);
        mkyb(yt);
      } else {
#pragma unroll
        for (int i = 0; i < 16; ++i) y[i] = y5[i];
        mkyb(y);
      }
    }
    s++;
    t0 = tend;
    k = kend + 1;
  }
  feval();
  store_rec(s);  // final {y_end, f_end}
#undef FV

  // ======================= phase 2: expand =================================
  // Per point p: lane = dim d; Hermite from LDS records; float4 stores.
  const int dw = lane >> 1, hi = lane & 1;
#pragma unroll 1
  for (int p = 0; p < 16; ++p) {
    const int ptp = p0 + p;
    if (ptp >= NPT) break;  // uniform: tail block
    const int q = b * NPT + ptp;
    const unsigned* rp = &recs[p * RSTRIDE];
    float* orow = outg + (size_t)q * (ND * NTOUT) + lane * NTOUT;
    const float o0 = y0g[q * ND + lane];  // exact k=0

    float y0v = 0.f, f0v = 0.f, y1v = 0.f, f1v = 0.f;
    int cur = -1;
#pragma unroll 1
    for (int kc = 0; kc < 6; ++kc) {
      float vals[4];
#pragma unroll
      for (int j = 0; j < 4; ++j) {
        const int kk = kc * 4 + j;
        if (kc == 0 && j == 0) {
          vals[0] = o0;
          continue;
        }
        const int ss = sidx[kk];   // uniform across wave
        if (ss != cur) {           // uniform branch, few reloads per point
          cur = ss;
          y0v = h16(rp[ss * 64 + dw], hi);
          f0v = h16(rp[ss * 64 + 32 + dw], hi);
          y1v = h16(rp[(ss + 1) * 64 + dw], hi);
          f1v = h16(rp[(ss + 1) * 64 + 32 + dw], hi);
        }
        vals[j] = fmaf(c0s[kk], y0v,
                  fmaf(c1s[kk], f0v,
                  fmaf(c2s[kk], y1v, c3s[kk] * f1v)));
      }
      *(float4*)&orow[kc * 4] = make_float4(vals[0], vals[1], vals[2], vals[3]);
    }
  }
}

extern "C" void kernel_launch(void* const* d_in, const int* in_sizes, int n_in,
                              void* d_out, int out_size, void* d_ws, size_t ws_size,
                              hipStream_t stream) {
  const float* y0 = (const float*)d_in[0];
  const float* ts = (const float*)d_in[1];
  const float* W1 = (const float*)d_in[2];
  const float* b1 = (const float*)d_in[3];
  const float* W2 = (const float*)d_in[4];
  const float* b2 = (const float*)d_in[5];
  float* out = (float*)d_out;

  hipLaunchKernelGGL(node_fused_kernel, dim3(NTASK), dim3(64), 0, stream,
                     y0, ts, W1, b1, W2, b2, out);
}